// Round 6
// baseline (91.932 us; speedup 1.0000x reference)
//
#include <hip/hip_runtime.h>
#include <math.h>

// Poincare contrastive loss, N=4096, D=8, TEMP=0.5.
// sim[i][j] = 1/(1+arcosh(x_ij)), x_ij = 1 + 2*sqdist/((1-sqc_i)(1-sqc_j))
// u = x-1 decomposed as u = A - 4*inv_sel*S,  S = z_i.z_j,
//   A = 2*inv_i*inv_j*(raw_i+raw_j), inv_sel = inv of the SMALLER index side
// e = exp(2*sim) via 368-seg PWL LUT on u (log2-indexed), built in prep.
// loss = mean_i -(2*sim[i,partner] - log(sum_{j!=i} e_ij))
//
// ROUND-16..18: LUT (-6us), colacc hoist (neutral), scalar Q (-3.5us).
// ROUND-19: R=4 amortization REGRESSED. ROUND-20: full-matrix 8-blocks/CU
//   (2048 blocks, no colacc/epilogue/atomics): per-element throughput 1.7x
//   better but 2x work -> neutral. Occupancy was not the stall.
// ROUND-21 (this round): the stall is LDS-gather bank conflicts. r1 PMC:
//   SQ_LDS_BANK_CONFLICT=1.5M over ~139K gathers = ~11 extra cy/gather ->
//   each LUT gather ~13-18cy on the per-CU LDS pipe; 2/col/wave x 64 col x
//   32 waves = 22-30us/CU = the entire pair wall. Fix: 4 bank-rotated LUT
//   copies in LDS (copy stride 372 float2 = 744 floats = +8 banks/copy),
//   lane reads copy (lane&3) -> hot-octave lanes spread over 4 disjoint
//   bank sets, ~4-8-way -> ~2-way (free per m136). 11.6KB LDS/block, fits
//   8 blocks/CU. Numerics bit-identical (exact replicas; self-cancel kept).
// Non-pair fixed: 39.5us harness 256MiB poison-fill - untouchable.

#define D 8
#define QS 12                // padded Q stride (floats) -> 48B, 16B-aligned
#define TWO_N 8192
#define HALF_N 4096
constexpr int BLOCK   = 256;
constexpr int JC      = 64;    // j-columns per block
constexpr int IBLOCKS = 16;    // 8192 / 512
constexpr int JCHUNKS = 128;   // 8192 / JC
constexpr int NBLK    = IBLOCKS * JCHUNKS;  // 2048 = 8 blocks/CU exactly
constexpr int NSEG  = 368;   // 23 octaves x 16 segments, u in [2^-16, 2^7)
constexpr int SEG_LO = 1776; // (111 << 4): bits>>19 of u = 2^-16
constexpr int NCOPY = 4;     // LDS LUT replicas
constexpr int CPAD  = 372;   // copy stride in float2: 744 floats = 8-bank rot
#define BOUNDARY (1.0f - 1e-5f)
#define LN2 0.6931471805599453f

typedef float f32x2 __attribute__((ext_vector_type(2)));

__device__ __forceinline__ float frcp(float x)  { return __builtin_amdgcn_rcpf(x); }
__device__ __forceinline__ float fsqrt(float x) { return __builtin_amdgcn_sqrtf(x); }
__device__ __forceinline__ float flog2(float x) { return __builtin_amdgcn_logf(x); }
__device__ __forceinline__ f32x2 splat(float v) { return (f32x2){v, v}; }

// DPP wave64 sum: result in lane 63.
__device__ __forceinline__ float dpp_wave_sum(float v) {
    int x;
    x = __builtin_amdgcn_update_dpp(0, __float_as_int(v), 0x111, 0xf, 0xf, false); // row_shr:1
    v += __int_as_float(x);
    x = __builtin_amdgcn_update_dpp(0, __float_as_int(v), 0x112, 0xf, 0xf, false); // row_shr:2
    v += __int_as_float(x);
    x = __builtin_amdgcn_update_dpp(0, __float_as_int(v), 0x114, 0xf, 0xe, false); // row_shr:4
    v += __int_as_float(x);
    x = __builtin_amdgcn_update_dpp(0, __float_as_int(v), 0x118, 0xf, 0xc, false); // row_shr:8
    v += __int_as_float(x);
    x = __builtin_amdgcn_update_dpp(0, __float_as_int(v), 0x142, 0xa, 0xf, false); // row_bcast:15
    v += __int_as_float(x);
    x = __builtin_amdgcn_update_dpp(0, __float_as_int(v), 0x143, 0xc, 0xf, false); // row_bcast:31
    v += __int_as_float(x);
    return v;   // lane 63 = full sum
}

// ---- prep: Q[row] = [z(8), inv, inv*raw, 0, 0]; zero out; build LUT ----
__global__ __launch_bounds__(256) void prep_kernel(
    const float* __restrict__ zi, const float* __restrict__ zj,
    float* __restrict__ q, float* __restrict__ out, float2* __restrict__ tab)
{
    const int row = blockIdx.x * 256 + threadIdx.x;
    const float* src = (row < HALF_N) ? (zi + (size_t)row * D)
                                      : (zj + (size_t)(row - HALF_N) * D);
    float4 a = *(const float4*)(src);
    float4 b = *(const float4*)(src + 4);
    float raw = a.x*a.x + a.y*a.y + a.z*a.z + a.w*a.w
              + b.x*b.x + b.y*b.y + b.z*b.z + b.w*b.w;
    float inv = frcp(1.0f - fminf(raw, BOUNDARY));
    float* dst = q + (size_t)row * QS;
    *(float4*)(dst)     = a;
    *(float4*)(dst + 4) = b;
    *(float4*)(dst + 8) = make_float4(inv, inv * raw, 0.0f, 0.0f);
    if (row == 0) out[0] = 0.0f;

    // build PWL LUT for g(u) = exp(2/(1+arcosh(1+u))), log2-spaced segments.
    if (row < NSEG) {
        const int m0 = row + SEG_LO;
        const int m1 = m0 + 1;
        float ua_f = __uint_as_float(((unsigned)(m0 >> 4) << 23) | ((unsigned)(m0 & 15) << 19));
        float ub_f = __uint_as_float(((unsigned)(m1 >> 4) << 23) | ((unsigned)(m1 & 15) << 19));
        double ua = (double)ua_f, ub = (double)ub_f;
        double ga = exp(2.0 / (1.0 + log(1.0 + ua + sqrt(ua * (ua + 2.0)))));
        double gb = exp(2.0 / (1.0 + log(1.0 + ub + sqrt(ub * (ub + 2.0)))));
        double sl = (gb - ga) / (ub - ua);
        double ic = ga - sl * ua;
        tab[row] = make_float2((float)sl, (float)ic);
    }
}

// e = exp(2*sim) via PWL table; u must be >= 0
__device__ __forceinline__ float lut1(float u, const float2* __restrict__ tab)
{
    int t = (int)(__float_as_uint(u) >> 19) - SEG_LO;
    t = (t < 0) ? 0 : t;
    t = (t > NSEG - 1) ? NSEG - 1 : t;
    float2 si = tab[t];
    return fmaf(si.x, u, si.y);
}

// MODE: 0 = all j > i (inv_sel = inv_i, per-lane reg)
//       1 = all j < i (inv_sel = inv_j, per-col scalar)
//       2 = diagonal overlap (per-element select)
template<int MODE>
__device__ __forceinline__ f32x2 tile_loop(
    const float* __restrict__ q, const float2* __restrict__ myTab, int jbase,
    const f32x2* __restrict__ s2, f32x2 t8, f32x2 t9, f32x2 m4,
    int irow0, int irow1)
{
    f32x2 acc = splat(0.0f);
    #pragma unroll 2
    for (int cc = 0; cc < JC; ++cc) {
        const float* qp = q + (size_t)(jbase + cc) * QS;   // wave-uniform
        float4 za = *(const float4*)(qp);
        float4 zb = *(const float4*)(qp + 4);
        float2 qc = *(const float2*)(qp + 8);              // {inv_j, inv_j*raw_j}

        f32x2 S = splat(0.0f);                             // z_i . z_j
        S = __builtin_elementwise_fma(s2[0], splat(za.x), S);
        S = __builtin_elementwise_fma(s2[1], splat(za.y), S);
        S = __builtin_elementwise_fma(s2[2], splat(za.z), S);
        S = __builtin_elementwise_fma(s2[3], splat(za.w), S);
        S = __builtin_elementwise_fma(s2[4], splat(zb.x), S);
        S = __builtin_elementwise_fma(s2[5], splat(zb.y), S);
        S = __builtin_elementwise_fma(s2[6], splat(zb.z), S);
        S = __builtin_elementwise_fma(s2[7], splat(zb.w), S);

        f32x2 A = t8 * splat(qc.x);                        // 2*inv_i*raw_i*inv_j
        A = __builtin_elementwise_fma(t9, splat(qc.y), A); // + 2*inv_i*inv_j*raw_j

        f32x2 msel;
        if (MODE == 0) {
            msel = m4;                                     // -4*inv_i
        } else {
            const float nm = -4.0f * qc.x;                 // -4*inv_j
            if (MODE == 1) {
                msel = splat(nm);
            } else {
                const int j = jbase + cc;
                msel.x = (j > irow0) ? m4.x : nm;
                msel.y = (j > irow1) ? m4.y : nm;
            }
        }
        f32x2 u = __builtin_elementwise_fma(S, msel, A);
        u = __builtin_elementwise_max(u, splat(0.0f));
        acc.x += lut1(u.x, myTab);
        acc.y += lut1(u.y, myTab);
    }
    return acc;
}

// ---- full-matrix pair kernel: 2048 blocks (8/CU), 4-copy LDS LUT ----
__global__ __launch_bounds__(BLOCK, 8) void pair_kernel(
    const float* __restrict__ q, const float2* __restrict__ gtab,
    float* __restrict__ part)
{
    __shared__ alignas(16) float2 stab[NCOPY * CPAD];  // 11.6 KB, bank-rotated

    const int tid   = threadIdx.x;
    const int ib    = blockIdx.x >> 7;               // i-block (16)
    const int jc    = blockIdx.x & (JCHUNKS - 1);    // j-chunk (128)
    const int ibase = ib * 512;
    const int jbase = jc * JC;

    // stage 4 exact replicas (184 float4 each; 736 float4 total, 3 rounds)
    {
        const float4* g4 = (const float4*)gtab;
        #pragma unroll
        for (int r = 0; r < 3; ++r) {
            int idx = r * BLOCK + tid;                  // 0..735
            if (idx < NCOPY * (NSEG / 2)) {
                int copy = idx / (NSEG / 2);
                int off  = idx % (NSEG / 2);
                ((float4*)(stab + copy * CPAD))[off] = g4[off];
            }
        }
    }

    // own two rows
    const int irow0 = ibase + tid;
    const int irow1 = irow0 + 256;
    f32x2 s2[8], t8, t9, m4;
    {
        const float* q0 = q + (size_t)irow0 * QS;
        const float* q1 = q + (size_t)irow1 * QS;
        float4 a0 = *(const float4*)(q0), b0 = *(const float4*)(q0 + 4);
        float2 c0 = *(const float2*)(q0 + 8);
        float4 a1 = *(const float4*)(q1), b1 = *(const float4*)(q1 + 4);
        float2 c1 = *(const float2*)(q1 + 8);
        s2[0] = (f32x2){a0.x, a1.x}; s2[1] = (f32x2){a0.y, a1.y};
        s2[2] = (f32x2){a0.z, a1.z}; s2[3] = (f32x2){a0.w, a1.w};
        s2[4] = (f32x2){b0.x, b1.x}; s2[5] = (f32x2){b0.y, b1.y};
        s2[6] = (f32x2){b0.z, b1.z}; s2[7] = (f32x2){b0.w, b1.w};
        t8 = (f32x2){2.0f * c0.y, 2.0f * c1.y};   // 2*inv*raw
        t9 = (f32x2){2.0f * c0.x, 2.0f * c1.x};   // 2*inv
        m4 = (f32x2){-4.0f * c0.x, -4.0f * c1.x}; // -4*inv
    }
    __syncthreads();   // stab ready

    const float2* myTab = stab + (tid & (NCOPY - 1)) * CPAD;  // lane's replica

    f32x2 acc;
    if (jbase >= ibase + 512)
        acc = tile_loop<0>(q, myTab, jbase, s2, t8, t9, m4, irow0, irow1);
    else if (jbase + JC <= ibase)
        acc = tile_loop<1>(q, myTab, jbase, s2, t8, t9, m4, irow0, irow1);
    else
        acc = tile_loop<2>(q, myTab, jbase, s2, t8, t9, m4, irow0, irow1);

    // coalesced partial row sums (includes j==i; reduce subtracts it)
    part[(size_t)jc * TWO_N + irow0] = acc.x;
    part[(size_t)jc * TWO_N + irow1] = acc.y;
}

// ---- epilogue: 32 blocks x 256; rowsum from partials, subtract self ----
__global__ __launch_bounds__(256) void reduce_kernel(
    const float* __restrict__ zi, const float* __restrict__ zj,
    const float* __restrict__ part, const float2* __restrict__ gtab,
    float* __restrict__ out)
{
    __shared__ float swred[4];
    const int tid = threadIdx.x;
    const int i   = blockIdx.x * 256 + tid;

    // sum the 128 j-chunk partials for this row (coalesced across lanes)
    float rs = 0.0f;
    {
        const float* pp = part + i;
        #pragma unroll 8
        for (int c = 0; c < JCHUNKS; ++c) rs += pp[(size_t)c * TWO_N];
    }

    const int base = (i < HALF_N) ? i : (i - HALF_N);
    const float* pa = (i < HALF_N) ? (zi + (size_t)base * D) : (zj + (size_t)base * D);
    const float* pb = (i < HALF_N) ? (zj + (size_t)base * D) : (zi + (size_t)base * D);
    float4 a0 = *(const float4*)(pa), a1 = *(const float4*)(pa + 4);
    float4 b0 = *(const float4*)(pb), b1 = *(const float4*)(pb + 4);
    float rawa = a0.x*a0.x + a0.y*a0.y + a0.z*a0.z + a0.w*a0.w
               + a1.x*a1.x + a1.y*a1.y + a1.z*a1.z + a1.w*a1.w;
    float rawb = b0.x*b0.x + b0.y*b0.y + b0.z*b0.z + b0.w*b0.w
               + b1.x*b1.x + b1.y*b1.y + b1.z*b1.z + b1.w*b1.w;
    float dot  = a0.x*b0.x + a0.y*b0.y + a0.z*b0.z + a0.w*b0.w
               + a1.x*b1.x + a1.y*b1.y + a1.z*b1.z + a1.w*b1.w;
    float sqd  = fmaxf(rawa + rawb - 2.0f * dot, 0.0f);
    float inva = frcp(1.0f - fminf(rawa, BOUNDARY));
    float invb = frcp(1.0f - fminf(rawb, BOUNDARY));
    float x    = fmaf(2.0f * sqd, inva * invb, 1.0f);
    float t    = fmaf(x, x, -1.0f);
    float s    = fsqrt(fmaxf(t, 0.0f));
    float dist = flog2(x + s) * LN2;
    float sim  = frcp(1.0f + dist);               // positive pair similarity

    // self term, mirroring pair's u = fma(S, -4*inv, A) with S=raw, A=4*inv^2*raw
    float cy = inva * rawa;
    float A  = (2.0f * cy) * inva;
    A = fmaf(2.0f * inva, cy, A);
    float us = fmaxf(fmaf(rawa, -4.0f * inva, A), 0.0f);
    float es = lut1(us, gtab);                    // same PWL -> exact cancel

    float denomv = rs - es;
    float dlog = flog2(denomv) * LN2;
    float term = -(2.0f * sim - dlog);

    float ws = dpp_wave_sum(term);
    if ((tid & 63) == 63) swred[tid >> 6] = ws;
    __syncthreads();
    if (tid == 0)
        atomicAdd(out, (swred[0] + swred[1] + swred[2] + swred[3])
                           * (1.0f / (float)TWO_N));
}

extern "C" void kernel_launch(void* const* d_in, const int* in_sizes, int n_in,
                              void* d_out, int out_size, void* d_ws, size_t ws_size,
                              hipStream_t stream) {
    const float* zi = (const float*)d_in[0];
    const float* zj = (const float*)d_in[1];

    float*  q    = (float*)d_ws;                        // [8192 * 12]
    float2* tab  = (float2*)(q + (size_t)TWO_N * QS);   // [368]
    float*  part = (float*)(tab + NSEG);                // [128 * 8192] = 4 MB

    prep_kernel<<<TWO_N / 256, 256, 0, stream>>>(zi, zj, q, (float*)d_out, tab);

    pair_kernel<<<NBLK, BLOCK, 0, stream>>>(q, tab, part);

    reduce_kernel<<<TWO_N / 256, 256, 0, stream>>>(zi, zj, part, tab, (float*)d_out);
}

// Round 7
// 88.063 us; speedup vs baseline: 1.0439x; 1.0439x over previous
//
#include <hip/hip_runtime.h>
#include <math.h>

// Poincare contrastive loss, N=4096, D=8, TEMP=0.5.
// sim[i][j] = 1/(1+arcosh(x_ij)), x_ij = 1 + 2*sqdist/((1-sqc_i)(1-sqc_j))
// u = x-1 decomposed as u = A - 4*inv_sel*S,  S = z_i.z_j,
//   A = 2*inv_i*inv_j*(raw_i+raw_j), inv_sel = inv of the SMALLER index side
// e = exp(2*sim) via 368-seg PWL LUT on u (log2-indexed), built in prep.
// loss = mean_i -(2*sim[i,partner] - log(sum_{j!=i} e_ij))
//
// ROUND-16..18: LUT (-6us), colacc hoist (neutral), scalar-Q grouped (-3.5us).
// ROUND-19: R=4 REGRESSED. ROUND-20: full-matrix 8/CU flat (neutral net,
//   1.7x per-pair). ROUND-21: 4-copy LUT replication neutral - bank math
//   shows same-segment reads were already FREE broadcasts and rotated copies
//   keep the distinct-segment collision rate -> invalid test, not a refute.
// ROUND-22 (this round): two mechanisms, both restoring/extending proven
//   wins: (a) r5's loop interleaved SMEM (scalarized uniform Q loads) with
//   DS gathers every iteration; SMEM+DS share lgkmcnt and SMEM retires OOO
//   -> every gather wait is a full lgkmcnt(0) SMEM drain, serializing
//   s_load latency with gather latency 64x. Restore r3's proven phase
//   separation: load a 4-column group (24 s_loads, one drain), then an
//   all-DS compute phase with counted waits. (b) LUT entries fp32x2->fp16x2:
//   b32 gathers touch 1 bank/lane (was 2), halving conflict opportunities
//   and LDS BW. Error: slope*u <= 0.15*g so fp16 slope err negligible;
//   intercept rounding ~3e-4 rel; total ~7e-4 (current 4e-4 passes with
//   margin). Reduce uses the same fp16 table -> self-term still cancels.
// Non-pair fixed: 39.5us harness 256MiB poison-fill - untouchable.

#define D 8
#define QS 12                // padded Q stride (floats) -> 48B, 16B-aligned
#define TWO_N 8192
#define HALF_N 4096
constexpr int BLOCK   = 256;
constexpr int JC      = 64;    // j-columns per block
constexpr int GRP     = 4;     // columns per load-group (SMEM/DS phase split)
constexpr int IBLOCKS = 16;    // 8192 / 512
constexpr int JCHUNKS = 128;   // 8192 / JC
constexpr int NBLK    = IBLOCKS * JCHUNKS;  // 2048 = 8 blocks/CU exactly
constexpr int NSEG  = 368;   // 23 octaves x 16 segments, u in [2^-16, 2^7)
constexpr int SEG_LO = 1776; // (111 << 4): bits>>19 of u = 2^-16
#define BOUNDARY (1.0f - 1e-5f)
#define LN2 0.6931471805599453f

typedef float    f32x2 __attribute__((ext_vector_type(2)));
typedef _Float16 f16x2 __attribute__((ext_vector_type(2)));

__device__ __forceinline__ float frcp(float x)  { return __builtin_amdgcn_rcpf(x); }
__device__ __forceinline__ float fsqrt(float x) { return __builtin_amdgcn_sqrtf(x); }
__device__ __forceinline__ float flog2(float x) { return __builtin_amdgcn_logf(x); }
__device__ __forceinline__ f32x2 splat(float v) { return (f32x2){v, v}; }

// DPP wave64 sum: result in lane 63.
__device__ __forceinline__ float dpp_wave_sum(float v) {
    int x;
    x = __builtin_amdgcn_update_dpp(0, __float_as_int(v), 0x111, 0xf, 0xf, false); // row_shr:1
    v += __int_as_float(x);
    x = __builtin_amdgcn_update_dpp(0, __float_as_int(v), 0x112, 0xf, 0xf, false); // row_shr:2
    v += __int_as_float(x);
    x = __builtin_amdgcn_update_dpp(0, __float_as_int(v), 0x114, 0xf, 0xe, false); // row_shr:4
    v += __int_as_float(x);
    x = __builtin_amdgcn_update_dpp(0, __float_as_int(v), 0x118, 0xf, 0xc, false); // row_shr:8
    v += __int_as_float(x);
    x = __builtin_amdgcn_update_dpp(0, __float_as_int(v), 0x142, 0xa, 0xf, false); // row_bcast:15
    v += __int_as_float(x);
    x = __builtin_amdgcn_update_dpp(0, __float_as_int(v), 0x143, 0xc, 0xf, false); // row_bcast:31
    v += __int_as_float(x);
    return v;   // lane 63 = full sum
}

// ---- prep: Q[row] = [z(8), inv, inv*raw, 0, 0]; zero out; build f16 LUT ----
__global__ __launch_bounds__(256) void prep_kernel(
    const float* __restrict__ zi, const float* __restrict__ zj,
    float* __restrict__ q, float* __restrict__ out, f16x2* __restrict__ tabh)
{
    const int row = blockIdx.x * 256 + threadIdx.x;
    const float* src = (row < HALF_N) ? (zi + (size_t)row * D)
                                      : (zj + (size_t)(row - HALF_N) * D);
    float4 a = *(const float4*)(src);
    float4 b = *(const float4*)(src + 4);
    float raw = a.x*a.x + a.y*a.y + a.z*a.z + a.w*a.w
              + b.x*b.x + b.y*b.y + b.z*b.z + b.w*b.w;
    float inv = frcp(1.0f - fminf(raw, BOUNDARY));
    float* dst = q + (size_t)row * QS;
    *(float4*)(dst)     = a;
    *(float4*)(dst + 4) = b;
    *(float4*)(dst + 8) = make_float4(inv, inv * raw, 0.0f, 0.0f);
    if (row == 0) out[0] = 0.0f;

    // build PWL LUT for g(u) = exp(2/(1+arcosh(1+u))), log2-spaced segments.
    if (row < NSEG) {
        const int m0 = row + SEG_LO;
        const int m1 = m0 + 1;
        float ua_f = __uint_as_float(((unsigned)(m0 >> 4) << 23) | ((unsigned)(m0 & 15) << 19));
        float ub_f = __uint_as_float(((unsigned)(m1 >> 4) << 23) | ((unsigned)(m1 & 15) << 19));
        double ua = (double)ua_f, ub = (double)ub_f;
        double ga = exp(2.0 / (1.0 + log(1.0 + ua + sqrt(ua * (ua + 2.0)))));
        double gb = exp(2.0 / (1.0 + log(1.0 + ub + sqrt(ub * (ub + 2.0)))));
        double sl = (gb - ga) / (ub - ua);
        double ic = ga - sl * ua;
        tabh[row] = (f16x2){(_Float16)(float)sl, (_Float16)(float)ic};
    }
}

struct QCol { float4 a; float4 b; float2 c; };

// e = exp(2*sim) via fp16 PWL pair; u must be >= 0
__device__ __forceinline__ float lut1(float u, const f16x2* __restrict__ tab)
{
    int t = (int)(__float_as_uint(u) >> 19) - SEG_LO;
    t = (t < 0) ? 0 : t;
    t = (t > NSEG - 1) ? NSEG - 1 : t;
    f16x2 si = tab[t];
    return fmaf((float)si.x, u, (float)si.y);
}

// MODE: 0 = all j > i (inv_sel = inv_i, per-lane reg)
//       1 = all j < i (inv_sel = inv_j, per-col scalar)
//       2 = diagonal overlap (per-element select)
template<int MODE>
__device__ __forceinline__ f32x2 tile_loop(
    const float* __restrict__ q, const f16x2* __restrict__ stab, int jbase,
    const f32x2* __restrict__ s2, f32x2 t8, f32x2 t9, f32x2 m4,
    int irow0, int irow1)
{
    f32x2 accE = splat(0.0f), accO = splat(0.0f);
    #pragma unroll 2
    for (int g = 0; g < JC / GRP; ++g) {
        // phase 1: group's wave-uniform Q loads (SMEM) - one drain total
        QCol qg[GRP];
        #pragma unroll
        for (int c = 0; c < GRP; ++c) {
            const float* qp = q + (size_t)(jbase + g * GRP + c) * QS;
            qg[c].a = *(const float4*)(qp);
            qg[c].b = *(const float4*)(qp + 4);
            qg[c].c = *(const float2*)(qp + 8);
        }
        // phase 2: all-DS compute (gathers get counted lgkmcnt waits)
        #pragma unroll
        for (int c = 0; c < GRP; ++c) {
            f32x2 S = splat(0.0f);                             // z_i . z_j
            S = __builtin_elementwise_fma(s2[0], splat(qg[c].a.x), S);
            S = __builtin_elementwise_fma(s2[1], splat(qg[c].a.y), S);
            S = __builtin_elementwise_fma(s2[2], splat(qg[c].a.z), S);
            S = __builtin_elementwise_fma(s2[3], splat(qg[c].a.w), S);
            S = __builtin_elementwise_fma(s2[4], splat(qg[c].b.x), S);
            S = __builtin_elementwise_fma(s2[5], splat(qg[c].b.y), S);
            S = __builtin_elementwise_fma(s2[6], splat(qg[c].b.z), S);
            S = __builtin_elementwise_fma(s2[7], splat(qg[c].b.w), S);

            f32x2 A = t8 * splat(qg[c].c.x);                   // 2invi*rawi*invj
            A = __builtin_elementwise_fma(t9, splat(qg[c].c.y), A);

            f32x2 msel;
            if (MODE == 0) {
                msel = m4;                                     // -4*inv_i
            } else {
                const float nm = -4.0f * qg[c].c.x;            // -4*inv_j
                if (MODE == 1) {
                    msel = splat(nm);
                } else {
                    const int j = jbase + g * GRP + c;
                    msel.x = (j > irow0) ? m4.x : nm;
                    msel.y = (j > irow1) ? m4.y : nm;
                }
            }
            f32x2 u = __builtin_elementwise_fma(S, msel, A);
            u = __builtin_elementwise_max(u, splat(0.0f));
            if (c & 1) { accO.x += lut1(u.x, stab); accO.y += lut1(u.y, stab); }
            else       { accE.x += lut1(u.x, stab); accE.y += lut1(u.y, stab); }
        }
    }
    return accE + accO;
}

// ---- full-matrix pair kernel: 2048 blocks (8/CU), phase-split loads ----
__global__ __launch_bounds__(BLOCK, 8) void pair_kernel(
    const float* __restrict__ q, const f16x2* __restrict__ gtabh,
    float* __restrict__ part)
{
    __shared__ alignas(16) f16x2 stab[NSEG];   // 1.47 KB fp16 PWL table

    const int tid   = threadIdx.x;
    const int ib    = blockIdx.x >> 7;               // i-block (16)
    const int jc    = blockIdx.x & (JCHUNKS - 1);    // j-chunk (128)
    const int ibase = ib * 512;
    const int jbase = jc * JC;

    // stage table: 92 float4s
    if (tid < NSEG / 4)
        ((float4*)stab)[tid] = ((const float4*)gtabh)[tid];

    // own two rows
    const int irow0 = ibase + tid;
    const int irow1 = irow0 + 256;
    f32x2 s2[8], t8, t9, m4;
    {
        const float* q0 = q + (size_t)irow0 * QS;
        const float* q1 = q + (size_t)irow1 * QS;
        float4 a0 = *(const float4*)(q0), b0 = *(const float4*)(q0 + 4);
        float2 c0 = *(const float2*)(q0 + 8);
        float4 a1 = *(const float4*)(q1), b1 = *(const float4*)(q1 + 4);
        float2 c1 = *(const float2*)(q1 + 8);
        s2[0] = (f32x2){a0.x, a1.x}; s2[1] = (f32x2){a0.y, a1.y};
        s2[2] = (f32x2){a0.z, a1.z}; s2[3] = (f32x2){a0.w, a1.w};
        s2[4] = (f32x2){b0.x, b1.x}; s2[5] = (f32x2){b0.y, b1.y};
        s2[6] = (f32x2){b0.z, b1.z}; s2[7] = (f32x2){b0.w, b1.w};
        t8 = (f32x2){2.0f * c0.y, 2.0f * c1.y};   // 2*inv*raw
        t9 = (f32x2){2.0f * c0.x, 2.0f * c1.x};   // 2*inv
        m4 = (f32x2){-4.0f * c0.x, -4.0f * c1.x}; // -4*inv
    }
    __syncthreads();   // stab ready

    f32x2 acc;
    if (jbase >= ibase + 512)
        acc = tile_loop<0>(q, stab, jbase, s2, t8, t9, m4, irow0, irow1);
    else if (jbase + JC <= ibase)
        acc = tile_loop<1>(q, stab, jbase, s2, t8, t9, m4, irow0, irow1);
    else
        acc = tile_loop<2>(q, stab, jbase, s2, t8, t9, m4, irow0, irow1);

    // coalesced partial row sums (includes j==i; reduce subtracts it)
    part[(size_t)jc * TWO_N + irow0] = acc.x;
    part[(size_t)jc * TWO_N + irow1] = acc.y;
}

// ---- epilogue: 32 blocks x 256; rowsum from partials, subtract self ----
__global__ __launch_bounds__(256) void reduce_kernel(
    const float* __restrict__ zi, const float* __restrict__ zj,
    const float* __restrict__ part, const f16x2* __restrict__ gtabh,
    float* __restrict__ out)
{
    __shared__ float swred[4];
    const int tid = threadIdx.x;
    const int i   = blockIdx.x * 256 + tid;

    // sum the 128 j-chunk partials for this row (coalesced across lanes)
    float rs = 0.0f;
    {
        const float* pp = part + i;
        #pragma unroll 8
        for (int c = 0; c < JCHUNKS; ++c) rs += pp[(size_t)c * TWO_N];
    }

    const int base = (i < HALF_N) ? i : (i - HALF_N);
    const float* pa = (i < HALF_N) ? (zi + (size_t)base * D) : (zj + (size_t)base * D);
    const float* pb = (i < HALF_N) ? (zj + (size_t)base * D) : (zi + (size_t)base * D);
    float4 a0 = *(const float4*)(pa), a1 = *(const float4*)(pa + 4);
    float4 b0 = *(const float4*)(pb), b1 = *(const float4*)(pb + 4);
    float rawa = a0.x*a0.x + a0.y*a0.y + a0.z*a0.z + a0.w*a0.w
               + a1.x*a1.x + a1.y*a1.y + a1.z*a1.z + a1.w*a1.w;
    float rawb = b0.x*b0.x + b0.y*b0.y + b0.z*b0.z + b0.w*b0.w
               + b1.x*b1.x + b1.y*b1.y + b1.z*b1.z + b1.w*b1.w;
    float dot  = a0.x*b0.x + a0.y*b0.y + a0.z*b0.z + a0.w*b0.w
               + a1.x*b1.x + a1.y*b1.y + a1.z*b1.z + a1.w*b1.w;
    float sqd  = fmaxf(rawa + rawb - 2.0f * dot, 0.0f);
    float inva = frcp(1.0f - fminf(rawa, BOUNDARY));
    float invb = frcp(1.0f - fminf(rawb, BOUNDARY));
    float x    = fmaf(2.0f * sqd, inva * invb, 1.0f);
    float t    = fmaf(x, x, -1.0f);
    float s    = fsqrt(fmaxf(t, 0.0f));
    float dist = flog2(x + s) * LN2;
    float sim  = frcp(1.0f + dist);               // positive pair similarity

    // self term, mirroring pair's u = fma(S, -4*inv, A) with S=raw, A=4*inv^2*raw
    float cy = inva * rawa;
    float A  = (2.0f * cy) * inva;
    A = fmaf(2.0f * inva, cy, A);
    float us = fmaxf(fmaf(rawa, -4.0f * inva, A), 0.0f);
    // same fp16 PWL path as pair -> near-exact cancel
    int tt = (int)(__float_as_uint(us) >> 19) - SEG_LO;
    tt = (tt < 0) ? 0 : tt;
    tt = (tt > NSEG - 1) ? NSEG - 1 : tt;
    f16x2 sih = gtabh[tt];
    float es = fmaf((float)sih.x, us, (float)sih.y);

    float denomv = rs - es;
    float dlog = flog2(denomv) * LN2;
    float term = -(2.0f * sim - dlog);

    float ws = dpp_wave_sum(term);
    if ((tid & 63) == 63) swred[tid >> 6] = ws;
    __syncthreads();
    if (tid == 0)
        atomicAdd(out, (swred[0] + swred[1] + swred[2] + swred[3])
                           * (1.0f / (float)TWO_N));
}

extern "C" void kernel_launch(void* const* d_in, const int* in_sizes, int n_in,
                              void* d_out, int out_size, void* d_ws, size_t ws_size,
                              hipStream_t stream) {
    const float* zi = (const float*)d_in[0];
    const float* zj = (const float*)d_in[1];

    float* q    = (float*)d_ws;                         // [8192 * 12]
    f16x2* tabh = (f16x2*)(q + (size_t)TWO_N * QS);     // [368] (1.5 KB)
    float* part = (float*)((char*)tabh + 2048);         // [128 * 8192] = 4 MB

    prep_kernel<<<TWO_N / 256, 256, 0, stream>>>(zi, zj, q, (float*)d_out, tabh);

    pair_kernel<<<NBLK, BLOCK, 0, stream>>>(q, tabh, part);

    reduce_kernel<<<TWO_N / 256, 256, 0, stream>>>(zi, zj, part, tabh, (float*)d_out);
}

// Round 9
// 87.886 us; speedup vs baseline: 1.0460x; 1.0020x over previous
//
#include <hip/hip_runtime.h>

// Poincare contrastive loss, N=4096, D=8, TEMP=0.5.
// sim[i][j] = 1/(1+arcosh(x_ij)), x_ij = 1 + 2*sqdist/((1-sqc_i)(1-sqc_j))
// u = x-1 decomposed as u = A - 4*inv_sel*S,  S = z_i.z_j,
//   A = 2*inv_i*inv_j*(raw_i+raw_j), inv_sel = inv of the SMALLER index side
// e = exp(2*sim) via 368-seg fp16 PWL LUT on u (log2-indexed), built in LDS.
// loss = mean_i -(2*sim[i,partner] - log(sum_{j!=i} e_ij))
//
// HISTORY: LUT -6us; grouped scalar-Q loads -3.5us (r3+r7, reproduced);
//   fp16 LUT ok; R=4 regressed; full-matrix 8/CU neutral-then-kept (1.7x
//   per-pair); LUT replication invalid test; r8 cooperative fusion FAILED
//   (launch never ran under graph capture -> out=0, absmax=|ref|=9.06;
//   numerics never exercised; cooperative launch = unverifiable, dropped).
// ROUND-24 (this round): consolidate on the r7 PASSING structure + 3 safe
//   mechanisms: (1) LUT built per-block in LDS via f32 intrinsics (drops
//   global tab roundtrip + prep fp64 tail; node delta ~1e-6 << f16 quant);
//   (2) float-clamp u to [2^-16, 127] -> integer index needs no clamps
//   (-4 VALU / 2 elems in hot loop); (3) reduce widened to 64 blocks x 128.
// Non-pair fixed: 39.5us harness 256MiB poison-fill - untouchable.

#define D 8
#define QS 12                // padded Q stride (floats) -> 48B, 16B-aligned
#define TWO_N 8192
#define HALF_N 4096
constexpr int BLOCK   = 256;
constexpr int JC      = 64;    // j-columns per block
constexpr int GRP     = 4;     // columns per load-group (phase split)
constexpr int IBLOCKS = 16;    // 8192 / 512
constexpr int JCHUNKS = 128;   // 8192 / JC
constexpr int NBLK    = IBLOCKS * JCHUNKS;  // 2048 = 8 blocks/CU exactly
constexpr int NSEG  = 368;   // 23 octaves x 16 segments, u in [2^-16, 2^7)
constexpr int SEG_LO = 1776; // (111 << 4): bits>>19 of u = 2^-16
#define BOUNDARY (1.0f - 1e-5f)
#define LN2   0.6931471805599453f
#define LOG2E 1.4426950408889634f
#define UMIN  1.52587890625e-05f   // 2^-16 -> segment 0
#define UMAX  127.0f               // top-4 mantissa 1111, exp 133 -> segment 367

typedef float    f32x2 __attribute__((ext_vector_type(2)));
typedef _Float16 f16x2 __attribute__((ext_vector_type(2)));

__device__ __forceinline__ float frcp(float x)  { return __builtin_amdgcn_rcpf(x); }
__device__ __forceinline__ float fsqrt(float x) { return __builtin_amdgcn_sqrtf(x); }
__device__ __forceinline__ float flog2(float x) { return __builtin_amdgcn_logf(x); }
__device__ __forceinline__ float fexp2(float x) { return __builtin_amdgcn_exp2f(x); }
__device__ __forceinline__ f32x2 splat(float v) { return (f32x2){v, v}; }

// DPP wave64 sum: result in lane 63.
__device__ __forceinline__ float dpp_wave_sum(float v) {
    int x;
    x = __builtin_amdgcn_update_dpp(0, __float_as_int(v), 0x111, 0xf, 0xf, false); // row_shr:1
    v += __int_as_float(x);
    x = __builtin_amdgcn_update_dpp(0, __float_as_int(v), 0x112, 0xf, 0xf, false); // row_shr:2
    v += __int_as_float(x);
    x = __builtin_amdgcn_update_dpp(0, __float_as_int(v), 0x114, 0xf, 0xe, false); // row_shr:4
    v += __int_as_float(x);
    x = __builtin_amdgcn_update_dpp(0, __float_as_int(v), 0x118, 0xf, 0xc, false); // row_shr:8
    v += __int_as_float(x);
    x = __builtin_amdgcn_update_dpp(0, __float_as_int(v), 0x142, 0xa, 0xf, false); // row_bcast:15
    v += __int_as_float(x);
    x = __builtin_amdgcn_update_dpp(0, __float_as_int(v), 0x143, 0xc, 0xf, false); // row_bcast:31
    v += __int_as_float(x);
    return v;   // lane 63 = full sum
}

// g(u) = exp(2/(1+arcosh(1+u))), f32 fast-intrinsic eval (LUT node values)
__device__ __forceinline__ float gfun(float u) {
    float y = 1.0f + u + fsqrt(fmaf(u, u, 2.0f * u));
    float d = flog2(y) * LN2;                     // arcosh(1+u)
    return fexp2(2.0f * LOG2E * frcp(1.0f + d));
}

// build the 368-entry fp16 PWL table into LDS (deterministic across blocks)
template<int NTHREADS>
__device__ __forceinline__ void build_stab(f16x2* stab, int tid) {
    for (int e = tid; e < NSEG; e += NTHREADS) {
        const int m0 = e + SEG_LO;
        const int m1 = m0 + 1;
        float ua = __uint_as_float(((unsigned)(m0 >> 4) << 23) | ((unsigned)(m0 & 15) << 19));
        float ub = __uint_as_float(((unsigned)(m1 >> 4) << 23) | ((unsigned)(m1 & 15) << 19));
        float ga = gfun(ua), gb = gfun(ub);
        float sl = (gb - ga) / (ub - ua);
        float ic = fmaf(-sl, ua, ga);
        stab[e] = (f16x2){(_Float16)sl, (_Float16)ic};
    }
}

struct QCol { float4 a; float4 b; float2 c; };

// e = exp(2*sim) via fp16 PWL pair; caller guarantees u in [UMIN, UMAX]
__device__ __forceinline__ float lut1(float u, const f16x2* __restrict__ tab)
{
    int t = (int)(__float_as_uint(u) >> 19) - SEG_LO;   // no clamps needed
    f16x2 si = tab[t];
    return fmaf((float)si.x, u, (float)si.y);
}

// MODE: 0 = all j > i (inv_sel = inv_i, per-lane reg)
//       1 = all j < i (inv_sel = inv_j, per-col scalar)
//       2 = diagonal overlap (per-element select)
template<int MODE>
__device__ __forceinline__ f32x2 tile_loop(
    const float* __restrict__ q, const f16x2* __restrict__ stab, int jbase,
    const f32x2* __restrict__ s2, f32x2 t8, f32x2 t9, f32x2 m4,
    int irow0, int irow1)
{
    f32x2 accE = splat(0.0f), accO = splat(0.0f);
    #pragma unroll 2
    for (int g = 0; g < JC / GRP; ++g) {
        // phase 1: group's wave-uniform Q loads - one drain total
        QCol qg[GRP];
        #pragma unroll
        for (int c = 0; c < GRP; ++c) {
            const float* qp = q + (size_t)(jbase + g * GRP + c) * QS;
            qg[c].a = *(const float4*)(qp);
            qg[c].b = *(const float4*)(qp + 4);
            qg[c].c = *(const float2*)(qp + 8);
        }
        // phase 2: all-DS compute (gathers get counted lgkmcnt waits)
        #pragma unroll
        for (int c = 0; c < GRP; ++c) {
            f32x2 S = splat(0.0f);                             // z_i . z_j
            S = __builtin_elementwise_fma(s2[0], splat(qg[c].a.x), S);
            S = __builtin_elementwise_fma(s2[1], splat(qg[c].a.y), S);
            S = __builtin_elementwise_fma(s2[2], splat(qg[c].a.z), S);
            S = __builtin_elementwise_fma(s2[3], splat(qg[c].a.w), S);
            S = __builtin_elementwise_fma(s2[4], splat(qg[c].b.x), S);
            S = __builtin_elementwise_fma(s2[5], splat(qg[c].b.y), S);
            S = __builtin_elementwise_fma(s2[6], splat(qg[c].b.z), S);
            S = __builtin_elementwise_fma(s2[7], splat(qg[c].b.w), S);

            f32x2 A = t8 * splat(qg[c].c.x);                   // 2invi*rawi*invj
            A = __builtin_elementwise_fma(t9, splat(qg[c].c.y), A);

            f32x2 msel;
            if (MODE == 0) {
                msel = m4;                                     // -4*inv_i
            } else {
                const float nm = -4.0f * qg[c].c.x;            // -4*inv_j
                if (MODE == 1) {
                    msel = splat(nm);
                } else {
                    const int j = jbase + g * GRP + c;
                    msel.x = (j > irow0) ? m4.x : nm;
                    msel.y = (j > irow1) ? m4.y : nm;
                }
            }
            f32x2 u = __builtin_elementwise_fma(S, msel, A);
            u = __builtin_elementwise_max(u, splat(UMIN));     // float clamps:
            u = __builtin_elementwise_min(u, splat(UMAX));     // index needs none
            if (c & 1) { accO.x += lut1(u.x, stab); accO.y += lut1(u.y, stab); }
            else       { accE.x += lut1(u.x, stab); accE.y += lut1(u.y, stab); }
        }
    }
    return accE + accO;
}

// ---- prep: Q[row] = [z(8), inv, inv*raw, 0, 0]; zero out ----
__global__ __launch_bounds__(256) void prep_kernel(
    const float* __restrict__ zi, const float* __restrict__ zj,
    float* __restrict__ q, float* __restrict__ out)
{
    const int row = blockIdx.x * 256 + threadIdx.x;
    const float* src = (row < HALF_N) ? (zi + (size_t)row * D)
                                      : (zj + (size_t)(row - HALF_N) * D);
    float4 a = *(const float4*)(src);
    float4 b = *(const float4*)(src + 4);
    float raw = a.x*a.x + a.y*a.y + a.z*a.z + a.w*a.w
              + b.x*b.x + b.y*b.y + b.z*b.z + b.w*b.w;
    float inv = frcp(1.0f - fminf(raw, BOUNDARY));
    float* dst = q + (size_t)row * QS;
    *(float4*)(dst)     = a;
    *(float4*)(dst + 4) = b;
    *(float4*)(dst + 8) = make_float4(inv, inv * raw, 0.0f, 0.0f);
    if (row == 0) out[0] = 0.0f;
}

// ---- full-matrix pair kernel: 2048 blocks (8/CU), phase-split loads ----
__global__ __launch_bounds__(BLOCK, 8) void pair_kernel(
    const float* __restrict__ q, float* __restrict__ part)
{
    __shared__ alignas(16) f16x2 stab[NSEG];   // 1.47 KB fp16 PWL table

    const int tid   = threadIdx.x;
    const int ib    = blockIdx.x >> 7;               // i-block (16)
    const int jc    = blockIdx.x & (JCHUNKS - 1);    // j-chunk (128)
    const int ibase = ib * 512;
    const int jbase = jc * JC;

    build_stab<BLOCK>(stab, tid);

    // own two rows
    const int irow0 = ibase + tid;
    const int irow1 = irow0 + 256;
    f32x2 s2[8], t8, t9, m4;
    {
        const float* q0 = q + (size_t)irow0 * QS;
        const float* q1 = q + (size_t)irow1 * QS;
        float4 a0 = *(const float4*)(q0), b0 = *(const float4*)(q0 + 4);
        float2 c0 = *(const float2*)(q0 + 8);
        float4 a1 = *(const float4*)(q1), b1 = *(const float4*)(q1 + 4);
        float2 c1 = *(const float2*)(q1 + 8);
        s2[0] = (f32x2){a0.x, a1.x}; s2[1] = (f32x2){a0.y, a1.y};
        s2[2] = (f32x2){a0.z, a1.z}; s2[3] = (f32x2){a0.w, a1.w};
        s2[4] = (f32x2){b0.x, b1.x}; s2[5] = (f32x2){b0.y, b1.y};
        s2[6] = (f32x2){b0.z, b1.z}; s2[7] = (f32x2){b0.w, b1.w};
        t8 = (f32x2){2.0f * c0.y, 2.0f * c1.y};   // 2*inv*raw
        t9 = (f32x2){2.0f * c0.x, 2.0f * c1.x};   // 2*inv
        m4 = (f32x2){-4.0f * c0.x, -4.0f * c1.x}; // -4*inv
    }
    __syncthreads();   // stab ready

    f32x2 acc;
    if (jbase >= ibase + 512)
        acc = tile_loop<0>(q, stab, jbase, s2, t8, t9, m4, irow0, irow1);
    else if (jbase + JC <= ibase)
        acc = tile_loop<1>(q, stab, jbase, s2, t8, t9, m4, irow0, irow1);
    else
        acc = tile_loop<2>(q, stab, jbase, s2, t8, t9, m4, irow0, irow1);

    // coalesced partial row sums (includes j==i; reduce subtracts it)
    part[(size_t)jc * TWO_N + irow0] = acc.x;
    part[(size_t)jc * TWO_N + irow1] = acc.y;
}

// ---- epilogue: 64 blocks x 128; rowsum from partials, subtract self ----
__global__ __launch_bounds__(128) void reduce_kernel(
    const float* __restrict__ zi, const float* __restrict__ zj,
    const float* __restrict__ part, float* __restrict__ out)
{
    __shared__ alignas(16) f16x2 stab[NSEG];
    __shared__ float swred[2];
    const int tid = threadIdx.x;
    const int i   = blockIdx.x * 128 + tid;

    build_stab<128>(stab, tid);

    // sum the 128 j-chunk partials for this row (coalesced across lanes)
    float rs = 0.0f;
    {
        const float* pp = part + i;
        #pragma unroll 8
        for (int c = 0; c < JCHUNKS; ++c) rs += pp[(size_t)c * TWO_N];
    }

    const int base = (i < HALF_N) ? i : (i - HALF_N);
    const float* pa = (i < HALF_N) ? (zi + (size_t)base * D) : (zj + (size_t)base * D);
    const float* pb = (i < HALF_N) ? (zj + (size_t)base * D) : (zi + (size_t)base * D);
    float4 a0 = *(const float4*)(pa), a1 = *(const float4*)(pa + 4);
    float4 b0 = *(const float4*)(pb), b1 = *(const float4*)(pb + 4);
    float rawa = a0.x*a0.x + a0.y*a0.y + a0.z*a0.z + a0.w*a0.w
               + a1.x*a1.x + a1.y*a1.y + a1.z*a1.z + a1.w*a1.w;
    float rawb = b0.x*b0.x + b0.y*b0.y + b0.z*b0.z + b0.w*b0.w
               + b1.x*b1.x + b1.y*b1.y + b1.z*b1.z + b1.w*b1.w;
    float dot  = a0.x*b0.x + a0.y*b0.y + a0.z*b0.z + a0.w*b0.w
               + a1.x*b1.x + a1.y*b1.y + a1.z*b1.z + a1.w*b1.w;
    float sqd  = fmaxf(rawa + rawb - 2.0f * dot, 0.0f);
    float inva = frcp(1.0f - fminf(rawa, BOUNDARY));
    float invb = frcp(1.0f - fminf(rawb, BOUNDARY));
    float x    = fmaf(2.0f * sqd, inva * invb, 1.0f);
    float t    = fmaf(x, x, -1.0f);
    float s    = fsqrt(fmaxf(t, 0.0f));
    float dist = flog2(x + s) * LN2;
    float sim  = frcp(1.0f + dist);               // positive pair similarity

    __syncthreads();   // stab ready (built above, used below)

    // self term, mirroring pair's u = fma(S, -4*inv, A) with S=raw,
    // then the same float clamps + PWL -> near-exact cancel
    float cy = inva * rawa;
    float A  = (2.0f * cy) * inva;
    A = fmaf(2.0f * inva, cy, A);
    float us = fmaf(rawa, -4.0f * inva, A);
    us = fminf(fmaxf(us, UMIN), UMAX);
    float es = lut1(us, stab);

    float denomv = rs - es;
    float dlog = flog2(denomv) * LN2;
    float term = -(2.0f * sim - dlog);

    float ws = dpp_wave_sum(term);
    if ((tid & 63) == 63) swred[tid >> 6] = ws;
    __syncthreads();
    if (tid == 0)
        atomicAdd(out, (swred[0] + swred[1]) * (1.0f / (float)TWO_N));
}

extern "C" void kernel_launch(void* const* d_in, const int* in_sizes, int n_in,
                              void* d_out, int out_size, void* d_ws, size_t ws_size,
                              hipStream_t stream) {
    const float* zi = (const float*)d_in[0];
    const float* zj = (const float*)d_in[1];

    float* q    = (float*)d_ws;                         // [8192 * 12]
    float* part = q + (size_t)TWO_N * QS;               // [128 * 8192] = 4 MB

    prep_kernel<<<TWO_N / 256, 256, 0, stream>>>(zi, zj, q, (float*)d_out);

    pair_kernel<<<NBLK, BLOCK, 0, stream>>>(q, part);

    reduce_kernel<<<TWO_N / 128, 128, 0, stream>>>(zi, zj, part, (float*)d_out);
}